// Round 10
// baseline (4576.255 us; speedup 1.0000x reference)
//
#include <hip/hip_runtime.h>
#include <cstdint>

#define B_SZ 64
#define T_SZ 2048
#define F_SZ 256
#define H_SZ 512

typedef _Float16 f16x8 __attribute__((ext_vector_type(8)));
typedef float f32x4 __attribute__((ext_vector_type(4)));

#if defined(__has_builtin)
#if __has_builtin(__builtin_amdgcn_fdot2)
#define HAVE_FDOT2 1
#endif
#endif
#ifndef HAVE_FDOT2
#define HAVE_FDOT2 0
#endif

typedef _Float16 half2v __attribute__((ext_vector_type(2)));
union H2U { uint32_t u; half2v h; _Float16 e[2]; };

__device__ __forceinline__ float fdot2f(uint32_t a, uint32_t b, float c) {
  H2U ua, ub; ua.u = a; ub.u = b;
#if HAVE_FDOT2
  return __builtin_amdgcn_fdot2(ua.h, ub.h, c, false);
#else
  return c + (float)ua.e[0] * (float)ub.e[0] + (float)ua.e[1] * (float)ub.e[1];
#endif
}

__device__ __forceinline__ uint32_t pack2h(float x, float y) {
  H2U v; v.e[0] = (_Float16)x; v.e[1] = (_Float16)y; return v.u;
}

__device__ __forceinline__ float fast_tanh(float x) {
  float xc = fminf(9.0f, fmaxf(-9.0f, x));
  float e = __expf(2.0f * xc);
  return (e - 1.0f) / (e + 1.0f);
}

__device__ __forceinline__ f16x8 pack8(const float* p) {
  float4 v0 = *(const float4*)p;
  float4 v1 = *(const float4*)(p + 4);
  f16x8 a;
  a[0] = (_Float16)v0.x; a[1] = (_Float16)v0.y;
  a[2] = (_Float16)v0.z; a[3] = (_Float16)v0.w;
  a[4] = (_Float16)v1.x; a[5] = (_Float16)v1.y;
  a[6] = (_Float16)v1.z; a[7] = (_Float16)v1.w;
  return a;
}

// Raw per-step barrier: drain LDS ops only (h-exchange visibility). Global
// xp-loads / h-stores float across it with counted waits at their uses.
__device__ __forceinline__ void step_barrier() {
  asm volatile("s_waitcnt lgkmcnt(0)\n\ts_barrier" ::: "memory");
}

// ---------------------------------------------------------------------------
// Kernel 1: xp[m,n] = q·W_ih^T + b_ih + b_hh   (unchanged — not bottleneck)
// ---------------------------------------------------------------------------
__global__ __launch_bounds__(256) void proj_kernel(
    const float* __restrict__ q, const float* __restrict__ w_ih,
    const float* __restrict__ b_ih, const float* __restrict__ b_hh,
    float* __restrict__ xp) {
  __shared__ uint32_t lds_a[16][128 + 4];
  __shared__ uint32_t lds_b[16][128 + 4];
  const int tid = threadIdx.x;
  const int nt = blockIdx.x & 3;
  const int mt = blockIdx.x >> 2;
  const int m0 = mt * 128, n0 = nt * 128;
  const int tx = tid & 15, ty = tid >> 4;
  const int sr = tid >> 3, sc4 = tid & 7;

  float bias[8];
#pragma unroll
  for (int j = 0; j < 8; ++j) {
    int n = n0 + tx * 8 + j;
    bias[j] = b_ih[n] + b_hh[n];
  }
  float acc[8][8];
#pragma unroll
  for (int i = 0; i < 8; ++i)
#pragma unroll
    for (int j = 0; j < 8; ++j) acc[i][j] = 0.f;

  for (int k0 = 0; k0 < F_SZ; k0 += 32) {
#pragma unroll
    for (int i = 0; i < 4; ++i) {
      int r = sr + 32 * i;
      float4 v = *(const float4*)(q + (size_t)(m0 + r) * F_SZ + k0 + sc4 * 4);
      lds_a[sc4 * 2 + 0][r] = pack2h(v.x, v.y);
      lds_a[sc4 * 2 + 1][r] = pack2h(v.z, v.w);
      float4 w = *(const float4*)(w_ih + (size_t)(n0 + r) * F_SZ + k0 + sc4 * 4);
      lds_b[sc4 * 2 + 0][r] = pack2h(w.x, w.y);
      lds_b[sc4 * 2 + 1][r] = pack2h(w.z, w.w);
    }
    __syncthreads();
#pragma unroll
    for (int kp = 0; kp < 16; ++kp) {
      uint32_t a8[8], b8[8];
#pragma unroll
      for (int i = 0; i < 8; ++i) a8[i] = lds_a[kp][ty * 8 + i];
#pragma unroll
      for (int j = 0; j < 8; ++j) b8[j] = lds_b[kp][tx * 8 + j];
#pragma unroll
      for (int i = 0; i < 8; ++i)
#pragma unroll
        for (int j = 0; j < 8; ++j)
          acc[i][j] = fdot2f(a8[i], b8[j], acc[i][j]);
    }
    __syncthreads();
  }
#pragma unroll
  for (int i = 0; i < 8; ++i) {
    size_t row = (size_t)(m0 + ty * 8 + i);
    float4 o0, o1;
    o0.x = acc[i][0] + bias[0]; o0.y = acc[i][1] + bias[1];
    o0.z = acc[i][2] + bias[2]; o0.w = acc[i][3] + bias[3];
    o1.x = acc[i][4] + bias[4]; o1.y = acc[i][5] + bias[5];
    o1.z = acc[i][6] + bias[6]; o1.w = acc[i][7] + bias[7];
    *(float4*)(xp + row * H_SZ + n0 + tx * 8) = o0;
    *(float4*)(xp + row * H_SZ + n0 + tx * 8 + 4) = o1;
  }
}

// ---------------------------------------------------------------------------
// Kernel 2: recurrence via MFMA at 1 wave/SIMD (512 unified regs/wave).
// One 256-thread WG (4 waves) per batch row. Wave w owns rows 128w..128w+127
// as 8 row-tiles of mfma_f32_16x16x32_f16:
//   tiles 0..6: register-resident (af[7][16] = 448 regs, AGPR+VGPR mix —
//               MFMA reads both natively; write-once, MFMA-read-only)
//   tile  7:   LDS-resident (4 x 16 KB, lane-linear conflict-free b128)
// Per step per CU: 64 h-broadcast reads + 64 W-tile reads (vs 256 at r9's
// 2-wave/SIMD config) — the LDS unit was the binder.
// Each lane produces TWO rows: R1 = 128w + 16(m>>2)+4g+(m&3) (tiles 0-3)
// and R2 = R1+64 (tiles 4-7); two static 16->1 selects, two tanh.
// Registers alone pin 1 WG/CU (4 waves x 512 regs = whole file).
// C/D layout (HW-verified r3..r9): col=lane&15, row=(lane>>4)*4+reg.
// ---------------------------------------------------------------------------
__global__ __attribute__((amdgpu_flat_work_group_size(256, 256),
                          amdgpu_waves_per_eu(1, 1)))
void rnn_kernel(const float* __restrict__ w_hh, float* __restrict__ out) {
  extern __shared__ char smem[];
  uint4* lds_w = (uint4*)smem;                   // [4][16][64] frags (64 KB)
  _Float16* lds_h = (_Float16*)(smem + 65536);   // 2 x 512

  const int b = blockIdx.x;
  const int tid = threadIdx.x;
  const int w = tid >> 6;     // wave 0..3
  const int lane = tid & 63;
  const int m = lane & 15;    // A row within tile / C col
  const int g = lane >> 4;    // k-group / C row-group

  // --- register tiles 0..6: rows 128w + 16*tile + m ---
  f16x8 af[7][16];
#pragma unroll
  for (int tile = 0; tile < 7; ++tile) {
    const float* rowp = w_hh + (size_t)(128 * w + 16 * tile + m) * H_SZ;
#pragma unroll
    for (int kt = 0; kt < 16; ++kt)
      af[tile][kt] = pack8(rowp + kt * 32 + g * 8);
  }
  // --- LDS tile 7: rows 128w + 112 + m ---
  {
    const float* rowp = w_hh + (size_t)(128 * w + 112 + m) * H_SZ;
#pragma unroll
    for (int kt = 0; kt < 16; ++kt) {
      f16x8 a = pack8(rowp + kt * 32 + g * 8);
      lds_w[(w * 16 + kt) * 64 + lane] = __builtin_bit_cast(uint4, a);
    }
  }
  // h0 = 0, both buffers (256 threads x 4)
  lds_h[tid] = (_Float16)0.f;
  lds_h[256 + tid] = (_Float16)0.f;
  lds_h[512 + tid] = (_Float16)0.f;
  lds_h[768 + tid] = (_Float16)0.f;
  __syncthreads();

  // two output rows per lane
  const int r1 = 16 * (m >> 2) + 4 * g + (m & 3);  // local 0..63 (tiles 0-3)
  const int R1 = 128 * w + r1;
  const int R2 = R1 + 64;                          // tiles 4-7
  const bool b8 = (m & 8) != 0, b4 = (m & 4) != 0;
  const bool b2 = (m & 2) != 0, b1 = (m & 1) != 0;

  const uint4* lwp = lds_w + (w * 16) * 64 + lane;

  float* outb = out + (size_t)b * T_SZ * H_SZ;
  float xc1 = outb[R1], xc2 = outb[R2];  // xp for t=0
  float hl1 = 0.f, hl2 = 0.f;

#pragma unroll 1
  for (int t = 0; t < T_SZ; ++t) {
    // prefetch next xp (floats across the raw barrier)
    int tn = (t + 1 < T_SZ) ? t + 1 : t;
    float xn1 = outb[(size_t)tn * H_SZ + R1];
    float xn2 = outb[(size_t)tn * H_SZ + R2];

    const _Float16* hb = lds_h + (t & 1) * 512;
    f32x4 c0 = {0.f, 0.f, 0.f, 0.f}, c1 = c0, c2 = c0, c3 = c0;
    f32x4 c4 = c0, c5 = c0, c6 = c0, c7 = c0;
#define STEP_KT(kt)                                                           \
    {                                                                         \
      f16x8 bf = *(const f16x8*)(hb + (kt) * 32 + g * 8);                     \
      uint4 lf = lwp[(kt) * 64];                                              \
      c0 = __builtin_amdgcn_mfma_f32_16x16x32_f16(af[0][kt], bf, c0, 0, 0, 0);\
      c1 = __builtin_amdgcn_mfma_f32_16x16x32_f16(af[1][kt], bf, c1, 0, 0, 0);\
      c2 = __builtin_amdgcn_mfma_f32_16x16x32_f16(af[2][kt], bf, c2, 0, 0, 0);\
      c3 = __builtin_amdgcn_mfma_f32_16x16x32_f16(af[3][kt], bf, c3, 0, 0, 0);\
      c4 = __builtin_amdgcn_mfma_f32_16x16x32_f16(af[4][kt], bf, c4, 0, 0, 0);\
      c5 = __builtin_amdgcn_mfma_f32_16x16x32_f16(af[5][kt], bf, c5, 0, 0, 0);\
      c6 = __builtin_amdgcn_mfma_f32_16x16x32_f16(af[6][kt], bf, c6, 0, 0, 0);\
      c7 = __builtin_amdgcn_mfma_f32_16x16x32_f16(                            \
          __builtin_bit_cast(f16x8, lf), bf, c7, 0, 0, 0);                    \
    }
    STEP_KT(0)  STEP_KT(1)  STEP_KT(2)  STEP_KT(3)
    STEP_KT(4)  STEP_KT(5)  STEP_KT(6)  STEP_KT(7)
    STEP_KT(8)  STEP_KT(9)  STEP_KT(10) STEP_KT(11)
    STEP_KT(12) STEP_KT(13) STEP_KT(14) STEP_KT(15)
#undef STEP_KT

    // static 16->1 selects: tile = m>>2 (b8,b4), reg = m&3 (b2,b1)
    float p0 = b8 ? (b4 ? c3[0] : c2[0]) : (b4 ? c1[0] : c0[0]);
    float p1 = b8 ? (b4 ? c3[1] : c2[1]) : (b4 ? c1[1] : c0[1]);
    float p2 = b8 ? (b4 ? c3[2] : c2[2]) : (b4 ? c1[2] : c0[2]);
    float p3 = b8 ? (b4 ? c3[3] : c2[3]) : (b4 ? c1[3] : c0[3]);
    float v1 = b2 ? (b1 ? p3 : p2) : (b1 ? p1 : p0);

    float s0 = b8 ? (b4 ? c7[0] : c6[0]) : (b4 ? c5[0] : c4[0]);
    float s1 = b8 ? (b4 ? c7[1] : c6[1]) : (b4 ? c5[1] : c4[1]);
    float s2 = b8 ? (b4 ? c7[2] : c6[2]) : (b4 ? c5[2] : c4[2]);
    float s3 = b8 ? (b4 ? c7[3] : c6[3]) : (b4 ? c5[3] : c4[3]);
    float v2 = b2 ? (b1 ? s3 : s2) : (b1 ? s1 : s0);

    float h1 = fast_tanh(xc1 + v1);
    float h2 = fast_tanh(xc2 + v2);
    outb[(size_t)t * H_SZ + R1] = h1;                // floats past barrier
    outb[(size_t)t * H_SZ + R2] = h2;
    _Float16* hn = lds_h + ((t + 1) & 1) * 512;
    hn[R1] = (_Float16)h1;                           // drained by barrier
    hn[R2] = (_Float16)h2;
    hl1 = h1; hl2 = h2;
    xc1 = xn1; xc2 = xn2;
    step_barrier();
  }

  // hidden = h_{T-1}
  out[(size_t)B_SZ * T_SZ * H_SZ + (size_t)b * H_SZ + R1] = hl1;
  out[(size_t)B_SZ * T_SZ * H_SZ + (size_t)b * H_SZ + R2] = hl2;
}

extern "C" void kernel_launch(void* const* d_in, const int* in_sizes, int n_in,
                              void* d_out, int out_size, void* d_ws,
                              size_t ws_size, hipStream_t stream) {
  (void)in_sizes; (void)n_in; (void)out_size; (void)d_ws; (void)ws_size;
  const float* q    = (const float*)d_in[0];
  const float* w_ih = (const float*)d_in[1];
  const float* w_hh = (const float*)d_in[2];
  const float* b_ih = (const float*)d_in[3];
  const float* b_hh = (const float*)d_in[4];
  float* out = (float*)d_out;

  proj_kernel<<<dim3((B_SZ * T_SZ / 128) * (H_SZ / 128)), dim3(256), 0,
                stream>>>(q, w_ih, b_ih, b_hh, out);

  // 65536 (LDS W tile) + 2048 (h dbuf) = 67584 B dynamic LDS (>64 KB opt-in)
  hipFuncSetAttribute(reinterpret_cast<const void*>(rnn_kernel),
                      hipFuncAttributeMaxDynamicSharedMemorySize, 67584);
  rnn_kernel<<<dim3(B_SZ), dim3(256), 67584, stream>>>(w_hh, out);
}